// Round 12
// baseline (293.173 us; speedup 1.0000x reference)
//
#include <hip/hip_runtime.h>

#define NB 32
#define NP 24564
#define NO 50
#define NC 81
#define THR 0.5f
#define KA_CHUNK 1024
#define NCH 24   // ceil(NP / KA_CHUNK)

__device__ __forceinline__ float rl_f(float v, int j) {
  return __uint_as_float((unsigned)__builtin_amdgcn_readlane((int)__float_as_uint(v), j));
}
__device__ __forceinline__ float bp_f(float v, int j4) {
  return __uint_as_float((unsigned)__builtin_amdgcn_ds_bpermute(j4, (int)__float_as_uint(v)));
}

// ws: acc dbl[4]@0 | num_pos i32[32]@32 | accLb f[32]@160 | accCb f[32]@288
//     done i32@416 | arrive i32[32]@420 | bpc u64[NB*NO*NCH]@552
//     hdr=307760 (16B aligned) | mine f[NB*NP]

// ---------------- Kernel A: per-truth per-chunk best prior + init ----------
__global__ __launch_bounds__(256) void kA(
    const float* __restrict__ priors, const float* __restrict__ targets,
    unsigned long long* __restrict__ bpc,
    double* __restrict__ acc, int* __restrict__ num_pos,
    float* __restrict__ accLb, float* __restrict__ accCb,
    int* __restrict__ done, int* __restrict__ arrive) {
  __shared__ float4 s_pf[KA_CHUNK];
  __shared__ float s_t[NO * 5];
  __shared__ unsigned long long s_bp[256];
  const int b = blockIdx.y;
  const int tid = threadIdx.x;
  const int base = blockIdx.x * KA_CHUNK;

  if (blockIdx.x == 0 && b == 0) {
    if (tid < 4) acc[tid] = 0.0;
    else if (tid >= 32 && tid < 64) num_pos[tid - 32] = 0;
    else if (tid >= 64 && tid < 96) accLb[tid - 64] = 0.0f;
    else if (tid >= 96 && tid < 128) accCb[tid - 96] = 0.0f;
    else if (tid == 128) *done = 0;
    else if (tid >= 160 && tid < 192) arrive[tid - 160] = 0;
  }

  for (int i = tid; i < NO * 5; i += 256) s_t[i] = targets[b * NO * 5 + i];

  #pragma unroll
  for (int k = 0; k < KA_CHUNK / 256; ++k) {
    const int p = base + k * 256 + tid;
    float4 pf;
    if (p < NP) {
      const float4 pr = ((const float4*)priors)[p];
      pf = make_float4(pr.x - pr.z * 0.5f, pr.y - pr.w * 0.5f,
                       pr.x + pr.z * 0.5f, pr.y + pr.w * 0.5f);
    } else {
      pf = make_float4(3.0f, 3.0f, 3.0f, 3.0f);  // degenerate: IoU == 0
    }
    s_pf[k * 256 + tid] = pf;
  }
  __syncthreads();

  const int wv = tid >> 6;
  const int lane = tid & 63;
  unsigned long long best = 0ull;
  if (lane < NO) {
    const float tx1 = s_t[lane * 5 + 0], ty1 = s_t[lane * 5 + 1];
    const float tx2 = s_t[lane * 5 + 2], ty2 = s_t[lane * 5 + 3];
    const float area_a = (tx2 - tx1) * (ty2 - ty1);
    const int i0 = wv * 256;
    #pragma unroll 8
    for (int i = 0; i < 256; ++i) {
      const float4 q = s_pf[i0 + i];
      const float wx = fmaxf(fminf(q.z, tx2) - fmaxf(q.x, tx1), 0.0f);
      const float wy = fmaxf(fminf(q.w, ty2) - fmaxf(q.y, ty1), 0.0f);
      const float inter = wx * wy;
      const float ab = (q.z - q.x) * (q.w - q.y);
      const float iou = __fdividef(inter, area_a + ab - inter);
      const unsigned p = (unsigned)(base + i0 + i);
      const unsigned long long pk =
          (((unsigned long long)__float_as_uint(iou)) << 32) |
          (unsigned long long)(0xFFFFFFFFu - p);
      if (pk > best) best = pk;
    }
  }
  s_bp[tid] = best;
  __syncthreads();
  if (tid < NO) {
    unsigned long long m = s_bp[tid];
    unsigned long long v = s_bp[64 + tid];  if (v > m) m = v;
    v = s_bp[128 + tid];                    if (v > m) m = v;
    v = s_bp[192 + tid];                    if (v > m) m = v;
    bpc[(size_t)(b * NO + tid) * NCH + blockIdx.x] = m;
  }
}

// ---------------- Kernel MS: match + lse + smooth-L1 + fused select --------
// grid (48, NB), 512 thr (8 waves x 64 rows). Last-arriver block per batch
// runs the top-K radix select (ex-kD); last of 32 selectors finalizes out.
__global__ __launch_bounds__(512) void kMS(
    const float* __restrict__ loc, const float* __restrict__ conf,
    const float* __restrict__ priors, const float* __restrict__ targets,
    const unsigned long long* __restrict__ bpc,
    float* __restrict__ mine, int* __restrict__ num_pos,
    float* __restrict__ accLb, float* __restrict__ accCb,
    int* __restrict__ arrive, int* __restrict__ done,
    double* __restrict__ acc, float* __restrict__ out) {
  __shared__ float s_s[512];
  __shared__ int s_tpb[NO];
  __shared__ float sLw[8], sCw[8];
  __shared__ int sNw[8];
  __shared__ int s_w[2][8];
  __shared__ double s_sd[8];
  __shared__ int s_sc[8];
  __shared__ int s_sel, s_fin;

  const int tid = threadIdx.x;
  const int lane = tid & 63;
  const int b = blockIdx.y;
  const int rowbase = blockIdx.x * 512 + (tid & ~63);
  const int p = rowbase + lane;
  const bool valid = (p < NP);
  const int pc = valid ? p : NP - 1;
  const size_t grow = (size_t)b * NP + pc;
  const float* tb = targets + (size_t)b * (NO * 5);

  // phase 0: reduce chunk slots per truth -> global-best prior per truth
  if (tid < NO) {
    const unsigned long long* sl = bpc + (size_t)(b * NO + tid) * NCH;
    unsigned long long m = 0ull;
    #pragma unroll
    for (int c = 0; c < NCH; ++c) {
      const unsigned long long v = sl[c];
      if (v > m) m = v;
    }
    s_tpb[tid] = (int)(0xFFFFFFFFu - (unsigned)(m & 0xFFFFFFFFull));
  }

  // lane l (<50) holds truth l in registers
  float ttx1 = 3.f, tty1 = 3.f, ttx2 = 3.f, tty2 = 3.f, tar = 0.f, tlab = 0.f;
  if (lane < NO) {
    ttx1 = tb[lane * 5 + 0]; tty1 = tb[lane * 5 + 1];
    ttx2 = tb[lane * 5 + 2]; tty2 = tb[lane * 5 + 3];
    tlab = tb[lane * 5 + 4];
    tar = (ttx2 - ttx1) * (tty2 - tty1);
  }
  const float4 pr = ((const float4*)priors)[pc];
  const float4 ldv = ((const float4*)loc)[grow];
  const float px1 = pr.x - pr.z * 0.5f, py1 = pr.y - pr.w * 0.5f;
  const float px2 = pr.x + pr.z * 0.5f, py2 = pr.y + pr.w * 0.5f;
  const float areab = (px2 - px1) * (py2 - py1);
  __syncthreads();
  const int tpb = (lane < NO) ? s_tpb[lane] : -1;

  // ---- lse pipeline setup ----------------------------------------------
  const int l16 = lane & 15;
  const int g4 = (lane >> 4) & 3;
  const int c0 = (4 - g4) & 3;           // 16B-aligned float4 base
  const int tc = (l16 < c0) ? l16 : (c0 + 64 + (l16 - c0));
  const float* cb = conf + (size_t)b * NP * NC;

  float4 v4[8];
  float vta[8], v80[8];

  #define KMS_ROWP(ph) (cb + (size_t)((rowbase + (ph) * 4 + g4) < NP \
      ? (rowbase + (ph) * 4 + g4) : (NP - 1)) * NC)
  #define KMS_ISSUE(ph) { const float* rp_ = KMS_ROWP(ph);            \
      v4[(ph) & 7] = *(const float4*)(rp_ + c0 + 4 * l16);            \
      vta[(ph) & 7] = rp_[tc]; v80[(ph) & 7] = rp_[80]; }

  KMS_ISSUE(0) KMS_ISSUE(1) KMS_ISSUE(2)
  KMS_ISSUE(3) KMS_ISSUE(4) KMS_ISSUE(5)
  __builtin_amdgcn_sched_barrier(0);

  // ---- match: memory-free 50-truth loop --------------------------------
  float bv = -1.0f;
  int bj = 0;
  #pragma unroll 2
  for (int j = 0; j < NO; ++j) {
    const float x1 = rl_f(ttx1, j), y1 = rl_f(tty1, j);
    const float x2 = rl_f(ttx2, j), y2 = rl_f(tty2, j);
    const float aa = rl_f(tar, j);
    const float wx = fmaxf(fminf(x2, px2) - fmaxf(x1, px1), 0.0f);
    const float wy = fmaxf(fminf(y2, py2) - fmaxf(y1, py1), 0.0f);
    const float inter = wx * wy;
    const float iou = __fdividef(inter, aa + areab - inter);
    if (iou > bv) { bv = iou; bj = j; }   // first-max tie-break
  }

  // ---- forced-match override via ballot scan (rare) --------------------
  int ovj = -1;
  unsigned long long M = __ballot((lane < NO) && ((unsigned)(tpb - rowbase) < 64u));
  while (M) {
    const int l = __ffsll((long long)M) - 1;
    M &= M - 1;
    const int r = __builtin_amdgcn_readlane(tpb, l) - rowbase;
    if (lane == r) ovj = l;              // ascending l -> last j wins
  }
  const int jm = (ovj >= 0) ? ovj : bj;
  const bool pos = valid && ((ovj >= 0) || (bv >= THR));
  const int j4 = jm << 2;
  const float lab = bp_f(tlab, j4);      // unconditional: all lanes active
  const float mx1 = bp_f(ttx1, j4), my1 = bp_f(tty1, j4);
  const float mx2 = bp_f(ttx2, j4), my2 = bp_f(tty2, j4);
  const int conft = pos ? ((int)lab + 1) : 0;

  // gather issued early so its latency hides under lse consume
  const float gval = conf[grow * NC + conft];

  // ---- smooth-L1 (positives only) --------------------------------------
  float sl1 = 0.0f;
  if (pos) {
    const float gcx = __fdividef((mx1 + mx2) * 0.5f - pr.x, 0.1f * pr.z);
    const float gcy = __fdividef((my1 + my2) * 0.5f - pr.y, 0.1f * pr.w);
    const float gw = __logf(__fdividef(mx2 - mx1, pr.z)) * 5.0f;
    const float gh = __logf(__fdividef(my2 - my1, pr.w)) * 5.0f;
    const float d0 = ldv.x - gcx, d1 = ldv.y - gcy;
    const float d2 = ldv.z - gw, d3 = ldv.w - gh;
    #pragma unroll
    for (int q = 0; q < 4; ++q) {
      const float d = (q == 0) ? d0 : (q == 1) ? d1 : (q == 2) ? d2 : d3;
      const float a = fabsf(d);
      sl1 += (a < 1.0f) ? 0.5f * d * d : a - 0.5f;
    }
  }

  // ---- lse consume: fully unrolled, issue ph+6 before consuming ph ------
  #pragma unroll
  for (int ph = 0; ph < 16; ++ph) {
    if (ph + 6 < 16) KMS_ISSUE(ph + 6)
    const float4 v = v4[ph & 7];
    float s = __expf(v.x) + __expf(v.y) + __expf(v.z) + __expf(v.w);
    s += __expf(vta[ph & 7]);
    const float e80 = __expf(v80[ph & 7]);
    s += (l16 == 0) ? e80 : 0.0f;
    s += __shfl_xor(s, 1, 64);
    s += __shfl_xor(s, 2, 64);
    s += __shfl_xor(s, 4, 64);
    s += __shfl_xor(s, 8, 64);
    if (l16 == 0) s_s[(tid & ~63) + ph * 4 + g4] = s;
  }
  const float myS = s_s[tid];            // wave-local; lgkmcnt ordered

  const float lca = __logf(myS) - gval;

  float sumL = 0.0f, sumC = 0.0f;
  int cnt = 0;
  if (valid) {
    mine[grow] = pos ? 0.0f : fmaxf(lca, 0.0f);
    if (pos) { cnt = 1; sumC = lca; sumL = sl1; }
  }

  // ---- wave + block reduce ----------------------------------------------
  #pragma unroll
  for (int m = 1; m <= 32; m <<= 1) {
    sumL += __shfl_xor(sumL, m, 64);
    sumC += __shfl_xor(sumC, m, 64);
    cnt  += __shfl_xor(cnt, m, 64);
  }
  const int w = tid >> 6;
  if (lane == 0) { sLw[w] = sumL; sCw[w] = sumC; sNw[w] = cnt; }
  __syncthreads();                       // also drains mine stores (vmcnt 0)
  if (tid == 0) {
    float L = 0.0f, C = 0.0f;
    int n = 0;
    #pragma unroll
    for (int q = 0; q < 8; ++q) { L += sLw[q]; C += sCw[q]; n += sNw[q]; }
    if (L != 0.0f) atomicAdd(&accLb[b], L);
    if (C != 0.0f) atomicAdd(&accCb[b], C);
    if (n) atomicAdd(&num_pos[b], n);
    __threadfence();                     // publish mine + sums (L2 wb)
    s_sel = (atomicAdd(&arrive[b], 1) == 47) ? 1 : 0;
  }
  __syncthreads();

  // ---- last-arriver block: top-K radix select for this batch ------------
  if (s_sel) {
    __threadfence();                     // acquire: invalidate stale caches
    const uint4* vb4 = (const uint4*)(mine + (size_t)b * NP);
    unsigned vals[48];
    #pragma unroll
    for (int k = 0; k < 12; ++k) {
      const int i = tid + k * 512;
      uint4 q = make_uint4(0u, 0u, 0u, 0u);
      if (i < NP / 4) q = vb4[i];        // NP/4 == 6141 exactly
      vals[4 * k + 0] = q.x; vals[4 * k + 1] = q.y;
      vals[4 * k + 2] = q.z; vals[4 * k + 3] = q.w;
    }
    const int K = min(3 * num_pos[b], NP - 1);

    unsigned prefix = 0u;
    int remaining = K;
    for (int bit = 30; bit >= 0; --bit) {
      const unsigned want = (prefix >> bit) | 1u;
      int cnt2 = 0;
      #pragma unroll
      for (int k = 0; k < 48; ++k) cnt2 += ((vals[k] >> bit) == want) ? 1 : 0;
      #pragma unroll
      for (int m = 32; m >= 1; m >>= 1) cnt2 += __shfl_xor(cnt2, m, 64);
      const int buf = bit & 1;
      if ((tid & 63) == 0) s_w[buf][tid >> 6] = cnt2;
      __syncthreads();
      int total = 0;
      #pragma unroll
      for (int q = 0; q < 8; ++q) total += s_w[buf][q];
      if (total >= remaining) prefix |= (1u << bit);
      else remaining -= total;
    }

    if (K > 0) {
      const float t = __uint_as_float(prefix);
      double sg = 0.0;
      int cg = 0;
      #pragma unroll
      for (int k = 0; k < 48; ++k) {
        const float f = __uint_as_float(vals[k]);
        if (f > t) { sg += (double)f; cg++; }
      }
      #pragma unroll
      for (int m = 32; m >= 1; m >>= 1) {
        sg += __shfl_xor(sg, m, 64);
        cg += __shfl_xor(cg, m, 64);
      }
      if ((tid & 63) == 0) { s_sd[tid >> 6] = sg; s_sc[tid >> 6] = cg; }
      __syncthreads();
      if (tid == 0) {
        double S = 0.0;
        int C2 = 0;
        #pragma unroll
        for (int q = 0; q < 8; ++q) { S += s_sd[q]; C2 += s_sc[q]; }
        S += (double)(K - C2) * (double)t;
        atomicAdd(&acc[2], S);
      }
    }

    // ---- last of 32 selectors finalizes ---------------------------------
    __syncthreads();
    if (tid == 0) {
      __threadfence();
      s_fin = (atomicAdd(done, 1) == NB - 1) ? 1 : 0;
    }
    __syncthreads();
    if (s_fin && tid < 64) {
      __threadfence();
      int n = 0;
      float L = 0.0f, C = 0.0f;
      if (tid < NB) { n = num_pos[tid]; L = accLb[tid]; C = accCb[tid]; }
      #pragma unroll
      for (int m = 32; m >= 1; m >>= 1) {
        n += __shfl_xor(n, m, 64);
        L += __shfl_xor(L, m, 64);
        C += __shfl_xor(C, m, 64);
      }
      if (tid == 0) {
        const double S = atomicAdd(&acc[2], 0.0);  // coherent read
        const double Nf = (double)n;
        out[0] = (float)((double)L / Nf);
        out[1] = (float)(((double)C + S) / Nf);
      }
    }
  }
}

extern "C" void kernel_launch(void* const* d_in, const int* in_sizes, int n_in,
                              void* d_out, int out_size, void* d_ws, size_t ws_size,
                              hipStream_t stream) {
  const float* loc     = (const float*)d_in[0];
  const float* conf    = (const float*)d_in[1];
  const float* priors  = (const float*)d_in[2];
  const float* targets = (const float*)d_in[3];
  float* out = (float*)d_out;

  char* ws = (char*)d_ws;
  double* acc   = (double*)ws;
  int* num_pos  = (int*)(ws + 32);
  float* accLb  = (float*)(ws + 160);
  float* accCb  = (float*)(ws + 288);
  int* done     = (int*)(ws + 416);
  int* arrive   = (int*)(ws + 420);
  unsigned long long* bpc = (unsigned long long*)(ws + 552);
  const size_t hdr = 307760;             // 552 + 307200, padded to 16B
  float* mine  = (float*)(ws + hdr);

  dim3 gA(NCH, NB);
  kA<<<gA, 256, 0, stream>>>(priors, targets, bpc,
                             acc, num_pos, accLb, accCb, done, arrive);

  dim3 gM((NP + 511) / 512, NB);
  kMS<<<gM, 512, 0, stream>>>(loc, conf, priors, targets, bpc,
                              mine, num_pos, accLb, accCb,
                              arrive, done, acc, out);
}

// Round 13
// 230.970 us; speedup vs baseline: 1.2693x; 1.2693x over previous
//
#include <hip/hip_runtime.h>

#define NB 32
#define NP 24564
#define NO 50
#define NC 81
#define THR 0.5f
#define KA_CHUNK 1024
#define NCH 24   // ceil(NP / KA_CHUNK)

__device__ __forceinline__ float rl_f(float v, int j) {
  return __uint_as_float((unsigned)__builtin_amdgcn_readlane((int)__float_as_uint(v), j));
}
__device__ __forceinline__ float bp_f(float v, int j4) {
  return __uint_as_float((unsigned)__builtin_amdgcn_ds_bpermute(j4, (int)__float_as_uint(v)));
}

// ws: acc dbl[4]@0 | num_pos i32[32]@32 | accLb f[32]@160 | accCb f[32]@288
//     done i32@416 | bpc u64[NB*NO*NCH]@552 | hdr=307760 | mine f[NB*NP]

// ---------------- Kernel A: per-truth per-chunk best prior + init ----------
__global__ __launch_bounds__(256) void kA(
    const float* __restrict__ priors, const float* __restrict__ targets,
    unsigned long long* __restrict__ bpc,
    double* __restrict__ acc, int* __restrict__ num_pos,
    float* __restrict__ accLb, float* __restrict__ accCb,
    int* __restrict__ done) {
  __shared__ float4 s_pf[KA_CHUNK];
  __shared__ float s_t[NO * 5];
  __shared__ unsigned long long s_bp[256];
  const int b = blockIdx.y;
  const int tid = threadIdx.x;
  const int base = blockIdx.x * KA_CHUNK;

  if (blockIdx.x == 0 && b == 0) {
    if (tid < 4) acc[tid] = 0.0;
    else if (tid >= 32 && tid < 64) num_pos[tid - 32] = 0;
    else if (tid >= 64 && tid < 96) accLb[tid - 64] = 0.0f;
    else if (tid >= 96 && tid < 128) accCb[tid - 96] = 0.0f;
    else if (tid == 128) *done = 0;
  }

  for (int i = tid; i < NO * 5; i += 256) s_t[i] = targets[b * NO * 5 + i];

  #pragma unroll
  for (int k = 0; k < KA_CHUNK / 256; ++k) {
    const int p = base + k * 256 + tid;
    float4 pf;
    if (p < NP) {
      const float4 pr = ((const float4*)priors)[p];
      pf = make_float4(pr.x - pr.z * 0.5f, pr.y - pr.w * 0.5f,
                       pr.x + pr.z * 0.5f, pr.y + pr.w * 0.5f);
    } else {
      pf = make_float4(3.0f, 3.0f, 3.0f, 3.0f);  // degenerate: IoU == 0
    }
    s_pf[k * 256 + tid] = pf;
  }
  __syncthreads();

  const int wv = tid >> 6;
  const int lane = tid & 63;
  unsigned long long best = 0ull;
  if (lane < NO) {
    const float tx1 = s_t[lane * 5 + 0], ty1 = s_t[lane * 5 + 1];
    const float tx2 = s_t[lane * 5 + 2], ty2 = s_t[lane * 5 + 3];
    const float area_a = (tx2 - tx1) * (ty2 - ty1);
    const int i0 = wv * 256;
    #pragma unroll 8
    for (int i = 0; i < 256; ++i) {
      const float4 q = s_pf[i0 + i];
      const float wx = fmaxf(fminf(q.z, tx2) - fmaxf(q.x, tx1), 0.0f);
      const float wy = fmaxf(fminf(q.w, ty2) - fmaxf(q.y, ty1), 0.0f);
      const float inter = wx * wy;
      const float ab = (q.z - q.x) * (q.w - q.y);
      const float iou = __fdividef(inter, area_a + ab - inter);
      const unsigned p = (unsigned)(base + i0 + i);
      const unsigned long long pk =
          (((unsigned long long)__float_as_uint(iou)) << 32) |
          (unsigned long long)(0xFFFFFFFFu - p);
      if (pk > best) best = pk;
    }
  }
  s_bp[tid] = best;
  __syncthreads();
  if (tid < NO) {
    unsigned long long m = s_bp[tid];
    unsigned long long v = s_bp[64 + tid];  if (v > m) m = v;
    v = s_bp[128 + tid];                    if (v > m) m = v;
    v = s_bp[192 + tid];                    if (v > m) m = v;
    bpc[(size_t)(b * NO + tid) * NCH + blockIdx.x] = m;
  }
}

// ---------------- Kernel MS: match + pipelined lse + smooth-L1 -------------
// grid (96, NB), 256 thr. ZERO barriers: each lane reduces its own truth's
// bpc slots (L2-hot), s_s is wave-local, epilogue = per-wave atomics.
__global__ __launch_bounds__(256) void kMS(
    const float* __restrict__ loc, const float* __restrict__ conf,
    const float* __restrict__ priors, const float* __restrict__ targets,
    const unsigned long long* __restrict__ bpc,
    float* __restrict__ mine, int* __restrict__ num_pos,
    float* __restrict__ accLb, float* __restrict__ accCb) {
  __shared__ float s_s[256];
  const int tid = threadIdx.x;
  const int lane = tid & 63;
  const int b = blockIdx.y;
  const int rowbase = blockIdx.x * 256 + (tid & 192);
  const int p = rowbase + lane;
  const bool valid = (p < NP);
  const int pc = valid ? p : NP - 1;
  const size_t grow = (size_t)b * NP + pc;
  const float* tb = targets + (size_t)b * (NO * 5);

  // lane l (<50): truth l in registers + own 24-slot bpc reduce (no LDS)
  float ttx1 = 3.f, tty1 = 3.f, ttx2 = 3.f, tty2 = 3.f, tar = 0.f, tlab = 0.f;
  int tpb = -1;
  if (lane < NO) {
    ttx1 = tb[lane * 5 + 0]; tty1 = tb[lane * 5 + 1];
    ttx2 = tb[lane * 5 + 2]; tty2 = tb[lane * 5 + 3];
    tlab = tb[lane * 5 + 4];
    tar = (ttx2 - ttx1) * (tty2 - tty1);
    const unsigned long long* sl = bpc + (size_t)(b * NO + lane) * NCH;
    unsigned long long m = 0ull;
    #pragma unroll
    for (int c = 0; c < NCH; ++c) {
      const unsigned long long v = sl[c];
      if (v > m) m = v;
    }
    tpb = (int)(0xFFFFFFFFu - (unsigned)(m & 0xFFFFFFFFull));
  }
  const float4 pr = ((const float4*)priors)[pc];
  const float4 ldv = ((const float4*)loc)[grow];
  const float px1 = pr.x - pr.z * 0.5f, py1 = pr.y - pr.w * 0.5f;
  const float px2 = pr.x + pr.z * 0.5f, py2 = pr.y + pr.w * 0.5f;
  const float areab = (px2 - px1) * (py2 - py1);

  // ---- lse pipeline setup ----------------------------------------------
  const int l16 = lane & 15;
  const int g4 = (lane >> 4) & 3;
  const int c0 = (4 - g4) & 3;           // 16B-aligned float4 base
  const int tc = (l16 < c0) ? l16 : (c0 + 64 + (l16 - c0));
  const float* cb = conf + (size_t)b * NP * NC;

  float4 v4[8];
  float vta[8], v80[8];

  #define KMS_ROWP(ph) (cb + (size_t)((rowbase + (ph) * 4 + g4) < NP \
      ? (rowbase + (ph) * 4 + g4) : (NP - 1)) * NC)
  #define KMS_ISSUE(ph) { const float* rp_ = KMS_ROWP(ph);            \
      v4[(ph) & 7] = *(const float4*)(rp_ + c0 + 4 * l16);            \
      vta[(ph) & 7] = rp_[tc]; v80[(ph) & 7] = rp_[80]; }

  // prologue: 6 phases in flight; match compute hides their latency
  KMS_ISSUE(0) KMS_ISSUE(1) KMS_ISSUE(2)
  KMS_ISSUE(3) KMS_ISSUE(4) KMS_ISSUE(5)
  __builtin_amdgcn_sched_barrier(0);

  // ---- match: memory-free 50-truth loop --------------------------------
  float bv = -1.0f;
  int bj = 0;
  #pragma unroll 2
  for (int j = 0; j < NO; ++j) {
    const float x1 = rl_f(ttx1, j), y1 = rl_f(tty1, j);
    const float x2 = rl_f(ttx2, j), y2 = rl_f(tty2, j);
    const float aa = rl_f(tar, j);
    const float wx = fmaxf(fminf(x2, px2) - fmaxf(x1, px1), 0.0f);
    const float wy = fmaxf(fminf(y2, py2) - fmaxf(y1, py1), 0.0f);
    const float inter = wx * wy;
    const float iou = __fdividef(inter, aa + areab - inter);
    if (iou > bv) { bv = iou; bj = j; }   // first-max tie-break
  }

  // ---- forced-match override via ballot scan (rare) --------------------
  int ovj = -1;
  unsigned long long M = __ballot((lane < NO) && ((unsigned)(tpb - rowbase) < 64u));
  while (M) {
    const int l = __ffsll((long long)M) - 1;
    M &= M - 1;
    const int r = __builtin_amdgcn_readlane(tpb, l) - rowbase;
    if (lane == r) ovj = l;              // ascending l -> last j wins
  }
  const int jm = (ovj >= 0) ? ovj : bj;
  const bool pos = valid && ((ovj >= 0) || (bv >= THR));
  const int j4 = jm << 2;
  const float lab = bp_f(tlab, j4);      // unconditional: all lanes active
  const float mx1 = bp_f(ttx1, j4), my1 = bp_f(tty1, j4);
  const float mx2 = bp_f(ttx2, j4), my2 = bp_f(tty2, j4);
  const int conft = pos ? ((int)lab + 1) : 0;

  // ---- smooth-L1 (positives only) --------------------------------------
  float sl1 = 0.0f;
  if (pos) {
    const float gcx = __fdividef((mx1 + mx2) * 0.5f - pr.x, 0.1f * pr.z);
    const float gcy = __fdividef((my1 + my2) * 0.5f - pr.y, 0.1f * pr.w);
    const float gw = __logf(__fdividef(mx2 - mx1, pr.z)) * 5.0f;
    const float gh = __logf(__fdividef(my2 - my1, pr.w)) * 5.0f;
    const float d0 = ldv.x - gcx, d1 = ldv.y - gcy;
    const float d2 = ldv.z - gw, d3 = ldv.w - gh;
    #pragma unroll
    for (int q = 0; q < 4; ++q) {
      const float d = (q == 0) ? d0 : (q == 1) ? d1 : (q == 2) ? d2 : d3;
      const float a = fabsf(d);
      sl1 += (a < 1.0f) ? 0.5f * d * d : a - 0.5f;
    }
  }

  // ---- lse consume: fully unrolled, issue ph+6 before consuming ph ------
  #pragma unroll
  for (int ph = 0; ph < 16; ++ph) {
    if (ph + 6 < 16) KMS_ISSUE(ph + 6)
    const float4 v = v4[ph & 7];
    float s = __expf(v.x) + __expf(v.y) + __expf(v.z) + __expf(v.w);
    s += __expf(vta[ph & 7]);
    const float e80 = __expf(v80[ph & 7]);
    s += (l16 == 0) ? e80 : 0.0f;
    s += __shfl_xor(s, 1, 64);
    s += __shfl_xor(s, 2, 64);
    s += __shfl_xor(s, 4, 64);
    s += __shfl_xor(s, 8, 64);
    if (l16 == 0) s_s[(tid & 192) + ph * 4 + g4] = s;
  }
  const float myS = s_s[tid];            // wave-local; lgkmcnt ordered

  const float gval = conf[grow * NC + conft];
  const float lca = __logf(myS) - gval;

  float sumL = 0.0f, sumC = 0.0f;
  int cnt = 0;
  if (valid) {
    mine[grow] = pos ? 0.0f : fmaxf(lca, 0.0f);
    if (pos) { cnt = 1; sumC = lca; sumL = sl1; }
  }

  // ---- per-wave reduce + per-wave atomics (no barrier) -------------------
  #pragma unroll
  for (int m = 1; m <= 32; m <<= 1) {
    sumL += __shfl_xor(sumL, m, 64);
    sumC += __shfl_xor(sumC, m, 64);
    cnt  += __shfl_xor(cnt, m, 64);
  }
  if (lane == 0) {
    if (sumL != 0.0f) atomicAdd(&accLb[b], sumL);
    if (sumC != 0.0f) atomicAdd(&accCb[b], sumC);
    if (cnt) atomicAdd(&num_pos[b], cnt);
  }
}

// ---------------- Kernel D: top-K radix select + fused finalize ------------
__global__ __launch_bounds__(512) void kD(
    const float* __restrict__ mine, const int* __restrict__ num_pos,
    double* __restrict__ acc, int* __restrict__ done,
    const float* __restrict__ accLb, const float* __restrict__ accCb,
    float* __restrict__ out) {
  const int b = blockIdx.x;
  const int tid = threadIdx.x;
  const uint4* vb4 = (const uint4*)(mine + (size_t)b * NP);

  unsigned vals[48];
  #pragma unroll
  for (int k = 0; k < 12; ++k) {
    const int i = tid + k * 512;
    uint4 q = make_uint4(0u, 0u, 0u, 0u);
    if (i < NP / 4) q = vb4[i];          // NP/4 == 6141 exactly
    vals[4 * k + 0] = q.x; vals[4 * k + 1] = q.y;
    vals[4 * k + 2] = q.z; vals[4 * k + 3] = q.w;
  }

  const int K = min(3 * num_pos[b], NP - 1);

  __shared__ int s_w[2][8];
  unsigned prefix = 0u;
  int remaining = K;

  for (int bit = 30; bit >= 0; --bit) {
    const unsigned want = (prefix >> bit) | 1u;
    int cnt = 0;
    #pragma unroll
    for (int k = 0; k < 48; ++k) cnt += ((vals[k] >> bit) == want) ? 1 : 0;
    #pragma unroll
    for (int m = 32; m >= 1; m >>= 1) cnt += __shfl_xor(cnt, m, 64);
    const int buf = bit & 1;
    if ((tid & 63) == 0) s_w[buf][tid >> 6] = cnt;
    __syncthreads();
    int total = 0;
    #pragma unroll
    for (int w = 0; w < 8; ++w) total += s_w[buf][w];
    if (total >= remaining) prefix |= (1u << bit);
    else remaining -= total;
  }

  if (K > 0) {
    const float t = __uint_as_float(prefix);
    double sg = 0.0;
    int cg = 0;
    #pragma unroll
    for (int k = 0; k < 48; ++k) {
      const float f = __uint_as_float(vals[k]);
      if (f > t) { sg += (double)f; cg++; }
    }
    #pragma unroll
    for (int m = 32; m >= 1; m >>= 1) {
      sg += __shfl_xor(sg, m, 64);
      cg += __shfl_xor(cg, m, 64);
    }
    __shared__ double s_sd[8];
    __shared__ int s_sc[8];
    const int wid = tid >> 6;
    if ((tid & 63) == 0) { s_sd[wid] = sg; s_sc[wid] = cg; }
    __syncthreads();
    if (tid == 0) {
      double S = 0.0;
      int C = 0;
      for (int w = 0; w < 8; ++w) { S += s_sd[w]; C += s_sc[w]; }
      S += (double)(K - C) * (double)t;
      atomicAdd(&acc[2], S);
    }
  }

  // ---- last block finalizes ---------------------------------------------
  __shared__ int s_last;
  __syncthreads();
  if (tid == 0) {
    __threadfence();
    s_last = (atomicAdd(done, 1) == NB - 1) ? 1 : 0;
  }
  __syncthreads();
  if (s_last && tid < 64) {
    __threadfence();
    int n = 0;
    float L = 0.0f, C = 0.0f;
    if (tid < NB) { n = num_pos[tid]; L = accLb[tid]; C = accCb[tid]; }
    #pragma unroll
    for (int m = 32; m >= 1; m >>= 1) {
      n += __shfl_xor(n, m, 64);
      L += __shfl_xor(L, m, 64);
      C += __shfl_xor(C, m, 64);
    }
    if (tid == 0) {
      const double S = atomicAdd(&acc[2], 0.0);  // coherent read
      const double Nf = (double)n;
      out[0] = (float)((double)L / Nf);
      out[1] = (float)(((double)C + S) / Nf);
    }
  }
}

extern "C" void kernel_launch(void* const* d_in, const int* in_sizes, int n_in,
                              void* d_out, int out_size, void* d_ws, size_t ws_size,
                              hipStream_t stream) {
  const float* loc     = (const float*)d_in[0];
  const float* conf    = (const float*)d_in[1];
  const float* priors  = (const float*)d_in[2];
  const float* targets = (const float*)d_in[3];
  float* out = (float*)d_out;

  char* ws = (char*)d_ws;
  double* acc   = (double*)ws;
  int* num_pos  = (int*)(ws + 32);
  float* accLb  = (float*)(ws + 160);
  float* accCb  = (float*)(ws + 288);
  int* done     = (int*)(ws + 416);
  unsigned long long* bpc = (unsigned long long*)(ws + 552);
  const size_t hdr = 307760;             // 552 + 307200, padded to 16B
  float* mine  = (float*)(ws + hdr);

  dim3 gA(NCH, NB);
  kA<<<gA, 256, 0, stream>>>(priors, targets, bpc,
                             acc, num_pos, accLb, accCb, done);

  dim3 gM((NP + 255) / 256, NB);
  kMS<<<gM, 256, 0, stream>>>(loc, conf, priors, targets, bpc,
                              mine, num_pos, accLb, accCb);

  kD<<<NB, 512, 0, stream>>>(mine, num_pos, acc, done, accLb, accCb, out);
}

// Round 14
// 145.708 us; speedup vs baseline: 2.0121x; 1.5852x over previous
//
#include <hip/hip_runtime.h>

#define NB 32
#define NP 24564
#define NO 50
#define NC 81
#define THR 0.5f
#define KA_CHUNK 1024
#define NCH 24   // ceil(NP / KA_CHUNK)

__device__ __forceinline__ float rl_f(float v, int j) {
  return __uint_as_float((unsigned)__builtin_amdgcn_readlane((int)__float_as_uint(v), j));
}
__device__ __forceinline__ float bp_f(float v, int j4) {
  return __uint_as_float((unsigned)__builtin_amdgcn_ds_bpermute(j4, (int)__float_as_uint(v)));
}

// ws: acc dbl[4]@0 | num_pos i32[32]@32 | accLb f[32]@160 | accCb f[32]@288
//     done i32@416 | bpc u64[NCH][NB*NO]@552 (TRANSPOSED) | hdr=307760 | mine

// ---------------- Kernel A: per-truth per-chunk best prior + init ----------
// bpc layout transposed: bpc[chunk * NB*NO + b*NO + j] -> coalesced writes
// in kA AND coalesced reads in kMS phase-0.
__global__ __launch_bounds__(256) void kA(
    const float* __restrict__ priors, const float* __restrict__ targets,
    unsigned long long* __restrict__ bpc,
    double* __restrict__ acc, int* __restrict__ num_pos,
    float* __restrict__ accLb, float* __restrict__ accCb,
    int* __restrict__ done) {
  __shared__ float4 s_pf[KA_CHUNK];
  __shared__ float s_t[NO * 5];
  __shared__ unsigned long long s_bp[256];
  const int b = blockIdx.y;
  const int tid = threadIdx.x;
  const int base = blockIdx.x * KA_CHUNK;

  if (blockIdx.x == 0 && b == 0) {
    if (tid < 4) acc[tid] = 0.0;
    else if (tid >= 32 && tid < 64) num_pos[tid - 32] = 0;
    else if (tid >= 64 && tid < 96) accLb[tid - 64] = 0.0f;
    else if (tid >= 96 && tid < 128) accCb[tid - 96] = 0.0f;
    else if (tid == 128) *done = 0;
  }

  for (int i = tid; i < NO * 5; i += 256) s_t[i] = targets[b * NO * 5 + i];

  #pragma unroll
  for (int k = 0; k < KA_CHUNK / 256; ++k) {
    const int p = base + k * 256 + tid;
    float4 pf;
    if (p < NP) {
      const float4 pr = ((const float4*)priors)[p];
      pf = make_float4(pr.x - pr.z * 0.5f, pr.y - pr.w * 0.5f,
                       pr.x + pr.z * 0.5f, pr.y + pr.w * 0.5f);
    } else {
      pf = make_float4(3.0f, 3.0f, 3.0f, 3.0f);  // degenerate: IoU == 0
    }
    s_pf[k * 256 + tid] = pf;
  }
  __syncthreads();

  const int wv = tid >> 6;
  const int lane = tid & 63;
  unsigned long long best = 0ull;
  if (lane < NO) {
    const float tx1 = s_t[lane * 5 + 0], ty1 = s_t[lane * 5 + 1];
    const float tx2 = s_t[lane * 5 + 2], ty2 = s_t[lane * 5 + 3];
    const float area_a = (tx2 - tx1) * (ty2 - ty1);
    const int i0 = wv * 256;
    #pragma unroll 8
    for (int i = 0; i < 256; ++i) {
      const float4 q = s_pf[i0 + i];
      const float wx = fmaxf(fminf(q.z, tx2) - fmaxf(q.x, tx1), 0.0f);
      const float wy = fmaxf(fminf(q.w, ty2) - fmaxf(q.y, ty1), 0.0f);
      const float inter = wx * wy;
      const float ab = (q.z - q.x) * (q.w - q.y);
      const float iou = __fdividef(inter, area_a + ab - inter);
      const unsigned p = (unsigned)(base + i0 + i);
      const unsigned long long pk =
          (((unsigned long long)__float_as_uint(iou)) << 32) |
          (unsigned long long)(0xFFFFFFFFu - p);
      if (pk > best) best = pk;
    }
  }
  s_bp[tid] = best;
  __syncthreads();
  if (tid < NO) {
    unsigned long long m = s_bp[tid];
    unsigned long long v = s_bp[64 + tid];  if (v > m) m = v;
    v = s_bp[128 + tid];                    if (v > m) m = v;
    v = s_bp[192 + tid];                    if (v > m) m = v;
    bpc[(size_t)blockIdx.x * (NB * NO) + b * NO + tid] = m;  // coalesced
  }
}

// ---------------- Kernel MS: match + pipelined lse + smooth-L1 -------------
// grid (48, NB), 512 thr (8 waves x 64 rows). R11 structure: s_tpb via one
// barrier; depth-6 pipelined lse; early gval; block-reduce epilogue.
__global__ __launch_bounds__(512) void kMS(
    const float* __restrict__ loc, const float* __restrict__ conf,
    const float* __restrict__ priors, const float* __restrict__ targets,
    const unsigned long long* __restrict__ bpc,
    float* __restrict__ mine, int* __restrict__ num_pos,
    float* __restrict__ accLb, float* __restrict__ accCb) {
  __shared__ float s_s[512];
  __shared__ int s_tpb[NO];
  __shared__ float sLw[8], sCw[8];
  __shared__ int sNw[8];

  const int tid = threadIdx.x;
  const int lane = tid & 63;
  const int b = blockIdx.y;
  const int rowbase = blockIdx.x * 512 + (tid & ~63);
  const int p = rowbase + lane;
  const bool valid = (p < NP);
  const int pc = valid ? p : NP - 1;
  const size_t grow = (size_t)b * NP + pc;
  const float* tb = targets + (size_t)b * (NO * 5);

  // phase 0: reduce chunk slots (transposed: consecutive per step, 7 lines)
  if (tid < NO) {
    unsigned long long m = 0ull;
    #pragma unroll
    for (int c = 0; c < NCH; ++c) {
      const unsigned long long v = bpc[(size_t)c * (NB * NO) + b * NO + tid];
      if (v > m) m = v;
    }
    s_tpb[tid] = (int)(0xFFFFFFFFu - (unsigned)(m & 0xFFFFFFFFull));
  }

  // lane l (<50) holds truth l in registers
  float ttx1 = 3.f, tty1 = 3.f, ttx2 = 3.f, tty2 = 3.f, tar = 0.f, tlab = 0.f;
  if (lane < NO) {
    ttx1 = tb[lane * 5 + 0]; tty1 = tb[lane * 5 + 1];
    ttx2 = tb[lane * 5 + 2]; tty2 = tb[lane * 5 + 3];
    tlab = tb[lane * 5 + 4];
    tar = (ttx2 - ttx1) * (tty2 - tty1);
  }
  const float4 pr = ((const float4*)priors)[pc];
  const float4 ldv = ((const float4*)loc)[grow];
  const float px1 = pr.x - pr.z * 0.5f, py1 = pr.y - pr.w * 0.5f;
  const float px2 = pr.x + pr.z * 0.5f, py2 = pr.y + pr.w * 0.5f;
  const float areab = (px2 - px1) * (py2 - py1);
  __syncthreads();
  const int tpb = (lane < NO) ? s_tpb[lane] : -1;

  // ---- lse pipeline setup ----------------------------------------------
  const int l16 = lane & 15;
  const int g4 = (lane >> 4) & 3;
  const int c0 = (4 - g4) & 3;           // 16B-aligned float4 base
  const int tc = (l16 < c0) ? l16 : (c0 + 64 + (l16 - c0));
  const float* cb = conf + (size_t)b * NP * NC;

  float4 v4[8];
  float vta[8], v80[8];

  #define KMS_ROWP(ph) (cb + (size_t)((rowbase + (ph) * 4 + g4) < NP \
      ? (rowbase + (ph) * 4 + g4) : (NP - 1)) * NC)
  #define KMS_ISSUE(ph) { const float* rp_ = KMS_ROWP(ph);            \
      v4[(ph) & 7] = *(const float4*)(rp_ + c0 + 4 * l16);            \
      vta[(ph) & 7] = rp_[tc]; v80[(ph) & 7] = rp_[80]; }

  KMS_ISSUE(0) KMS_ISSUE(1) KMS_ISSUE(2)
  KMS_ISSUE(3) KMS_ISSUE(4) KMS_ISSUE(5)
  __builtin_amdgcn_sched_barrier(0);

  // ---- match: memory-free 50-truth loop --------------------------------
  float bv = -1.0f;
  int bj = 0;
  #pragma unroll 2
  for (int j = 0; j < NO; ++j) {
    const float x1 = rl_f(ttx1, j), y1 = rl_f(tty1, j);
    const float x2 = rl_f(ttx2, j), y2 = rl_f(tty2, j);
    const float aa = rl_f(tar, j);
    const float wx = fmaxf(fminf(x2, px2) - fmaxf(x1, px1), 0.0f);
    const float wy = fmaxf(fminf(y2, py2) - fmaxf(y1, py1), 0.0f);
    const float inter = wx * wy;
    const float iou = __fdividef(inter, aa + areab - inter);
    if (iou > bv) { bv = iou; bj = j; }   // first-max tie-break
  }

  // ---- forced-match override via ballot scan (rare) --------------------
  int ovj = -1;
  unsigned long long M = __ballot((lane < NO) && ((unsigned)(tpb - rowbase) < 64u));
  while (M) {
    const int l = __ffsll((long long)M) - 1;
    M &= M - 1;
    const int r = __builtin_amdgcn_readlane(tpb, l) - rowbase;
    if (lane == r) ovj = l;              // ascending l -> last j wins
  }
  const int jm = (ovj >= 0) ? ovj : bj;
  const bool pos = valid && ((ovj >= 0) || (bv >= THR));
  const int j4 = jm << 2;
  const float lab = bp_f(tlab, j4);      // unconditional: all lanes active
  const float mx1 = bp_f(ttx1, j4), my1 = bp_f(tty1, j4);
  const float mx2 = bp_f(ttx2, j4), my2 = bp_f(tty2, j4);
  const int conft = pos ? ((int)lab + 1) : 0;

  // gather issued early so its latency hides under lse consume
  const float gval = conf[grow * NC + conft];

  // ---- smooth-L1 (positives only) --------------------------------------
  float sl1 = 0.0f;
  if (pos) {
    const float gcx = __fdividef((mx1 + mx2) * 0.5f - pr.x, 0.1f * pr.z);
    const float gcy = __fdividef((my1 + my2) * 0.5f - pr.y, 0.1f * pr.w);
    const float gw = __logf(__fdividef(mx2 - mx1, pr.z)) * 5.0f;
    const float gh = __logf(__fdividef(my2 - my1, pr.w)) * 5.0f;
    const float d0 = ldv.x - gcx, d1 = ldv.y - gcy;
    const float d2 = ldv.z - gw, d3 = ldv.w - gh;
    #pragma unroll
    for (int q = 0; q < 4; ++q) {
      const float d = (q == 0) ? d0 : (q == 1) ? d1 : (q == 2) ? d2 : d3;
      const float a = fabsf(d);
      sl1 += (a < 1.0f) ? 0.5f * d * d : a - 0.5f;
    }
  }

  // ---- lse consume: fully unrolled, issue ph+6 before consuming ph ------
  #pragma unroll
  for (int ph = 0; ph < 16; ++ph) {
    if (ph + 6 < 16) KMS_ISSUE(ph + 6)
    const float4 v = v4[ph & 7];
    float s = __expf(v.x) + __expf(v.y) + __expf(v.z) + __expf(v.w);
    s += __expf(vta[ph & 7]);
    const float e80 = __expf(v80[ph & 7]);
    s += (l16 == 0) ? e80 : 0.0f;
    s += __shfl_xor(s, 1, 64);
    s += __shfl_xor(s, 2, 64);
    s += __shfl_xor(s, 4, 64);
    s += __shfl_xor(s, 8, 64);
    if (l16 == 0) s_s[(tid & ~63) + ph * 4 + g4] = s;
  }
  const float myS = s_s[tid];            // wave-local; lgkmcnt ordered

  const float lca = __logf(myS) - gval;

  float sumL = 0.0f, sumC = 0.0f;
  int cnt = 0;
  if (valid) {
    mine[grow] = pos ? 0.0f : fmaxf(lca, 0.0f);
    if (pos) { cnt = 1; sumC = lca; sumL = sl1; }
  }

  // ---- wave + block reduce, one atomic set per block --------------------
  #pragma unroll
  for (int m = 1; m <= 32; m <<= 1) {
    sumL += __shfl_xor(sumL, m, 64);
    sumC += __shfl_xor(sumC, m, 64);
    cnt  += __shfl_xor(cnt, m, 64);
  }
  const int w = tid >> 6;
  if (lane == 0) { sLw[w] = sumL; sCw[w] = sumC; sNw[w] = cnt; }
  __syncthreads();
  if (tid == 0) {
    float L = 0.0f, C = 0.0f;
    int n = 0;
    #pragma unroll
    for (int q = 0; q < 8; ++q) { L += sLw[q]; C += sCw[q]; n += sNw[q]; }
    if (L != 0.0f) atomicAdd(&accLb[b], L);
    if (C != 0.0f) atomicAdd(&accCb[b], C);
    if (n) atomicAdd(&num_pos[b], n);
  }
}

// ---------------- Kernel D: top-K radix select + fused finalize ------------
__global__ __launch_bounds__(512) void kD(
    const float* __restrict__ mine, const int* __restrict__ num_pos,
    double* __restrict__ acc, int* __restrict__ done,
    const float* __restrict__ accLb, const float* __restrict__ accCb,
    float* __restrict__ out) {
  const int b = blockIdx.x;
  const int tid = threadIdx.x;
  const uint4* vb4 = (const uint4*)(mine + (size_t)b * NP);

  unsigned vals[48];
  #pragma unroll
  for (int k = 0; k < 12; ++k) {
    const int i = tid + k * 512;
    uint4 q = make_uint4(0u, 0u, 0u, 0u);
    if (i < NP / 4) q = vb4[i];          // NP/4 == 6141 exactly
    vals[4 * k + 0] = q.x; vals[4 * k + 1] = q.y;
    vals[4 * k + 2] = q.z; vals[4 * k + 3] = q.w;
  }

  const int K = min(3 * num_pos[b], NP - 1);

  __shared__ int s_w[2][8];
  unsigned prefix = 0u;
  int remaining = K;

  for (int bit = 30; bit >= 0; --bit) {
    const unsigned want = (prefix >> bit) | 1u;
    int cnt = 0;
    #pragma unroll
    for (int k = 0; k < 48; ++k) cnt += ((vals[k] >> bit) == want) ? 1 : 0;
    #pragma unroll
    for (int m = 32; m >= 1; m >>= 1) cnt += __shfl_xor(cnt, m, 64);
    const int buf = bit & 1;
    if ((tid & 63) == 0) s_w[buf][tid >> 6] = cnt;
    __syncthreads();
    int total = 0;
    #pragma unroll
    for (int w = 0; w < 8; ++w) total += s_w[buf][w];
    if (total >= remaining) prefix |= (1u << bit);
    else remaining -= total;
  }

  if (K > 0) {
    const float t = __uint_as_float(prefix);
    double sg = 0.0;
    int cg = 0;
    #pragma unroll
    for (int k = 0; k < 48; ++k) {
      const float f = __uint_as_float(vals[k]);
      if (f > t) { sg += (double)f; cg++; }
    }
    #pragma unroll
    for (int m = 32; m >= 1; m >>= 1) {
      sg += __shfl_xor(sg, m, 64);
      cg += __shfl_xor(cg, m, 64);
    }
    __shared__ double s_sd[8];
    __shared__ int s_sc[8];
    const int wid = tid >> 6;
    if ((tid & 63) == 0) { s_sd[wid] = sg; s_sc[wid] = cg; }
    __syncthreads();
    if (tid == 0) {
      double S = 0.0;
      int C = 0;
      for (int w = 0; w < 8; ++w) { S += s_sd[w]; C += s_sc[w]; }
      S += (double)(K - C) * (double)t;
      atomicAdd(&acc[2], S);
    }
  }

  // ---- last block finalizes ---------------------------------------------
  __shared__ int s_last;
  __syncthreads();
  if (tid == 0) {
    __threadfence();
    s_last = (atomicAdd(done, 1) == NB - 1) ? 1 : 0;
  }
  __syncthreads();
  if (s_last && tid < 64) {
    __threadfence();
    int n = 0;
    float L = 0.0f, C = 0.0f;
    if (tid < NB) { n = num_pos[tid]; L = accLb[tid]; C = accCb[tid]; }
    #pragma unroll
    for (int m = 32; m >= 1; m >>= 1) {
      n += __shfl_xor(n, m, 64);
      L += __shfl_xor(L, m, 64);
      C += __shfl_xor(C, m, 64);
    }
    if (tid == 0) {
      const double S = atomicAdd(&acc[2], 0.0);  // coherent read
      const double Nf = (double)n;
      out[0] = (float)((double)L / Nf);
      out[1] = (float)(((double)C + S) / Nf);
    }
  }
}

extern "C" void kernel_launch(void* const* d_in, const int* in_sizes, int n_in,
                              void* d_out, int out_size, void* d_ws, size_t ws_size,
                              hipStream_t stream) {
  const float* loc     = (const float*)d_in[0];
  const float* conf    = (const float*)d_in[1];
  const float* priors  = (const float*)d_in[2];
  const float* targets = (const float*)d_in[3];
  float* out = (float*)d_out;

  char* ws = (char*)d_ws;
  double* acc   = (double*)ws;
  int* num_pos  = (int*)(ws + 32);
  float* accLb  = (float*)(ws + 160);
  float* accCb  = (float*)(ws + 288);
  int* done     = (int*)(ws + 416);
  unsigned long long* bpc = (unsigned long long*)(ws + 552);
  const size_t hdr = 307760;             // 552 + 307200, padded to 16B
  float* mine  = (float*)(ws + hdr);

  dim3 gA(NCH, NB);
  kA<<<gA, 256, 0, stream>>>(priors, targets, bpc,
                             acc, num_pos, accLb, accCb, done);

  dim3 gM((NP + 511) / 512, NB);
  kMS<<<gM, 512, 0, stream>>>(loc, conf, priors, targets, bpc,
                              mine, num_pos, accLb, accCb);

  kD<<<NB, 512, 0, stream>>>(mine, num_pos, acc, done, accLb, accCb, out);
}

// Round 15
// 142.622 us; speedup vs baseline: 2.0556x; 1.0216x over previous
//
#include <hip/hip_runtime.h>

#define NB 32
#define NP 24564
#define NO 50
#define NC 81
#define THR 0.5f
#define KA_CHUNK 1024
#define NCH 24   // ceil(NP / KA_CHUNK)

__device__ __forceinline__ float rl_f(float v, int j) {
  return __uint_as_float((unsigned)__builtin_amdgcn_readlane((int)__float_as_uint(v), j));
}
__device__ __forceinline__ float bp_f(float v, int j4) {
  return __uint_as_float((unsigned)__builtin_amdgcn_ds_bpermute(j4, (int)__float_as_uint(v)));
}

// ws: acc dbl[4]@0 | num_pos i32[32]@32 | accLb f[32]@160 | accCb f[32]@288
//     done i32@416 | bpc u64[NCH][NB*NO]@552 (transposed) | hdr=307760 | mine

// ---------------- Kernel A: per-truth per-chunk best prior + init ----------
__global__ __launch_bounds__(256) void kA(
    const float* __restrict__ priors, const float* __restrict__ targets,
    unsigned long long* __restrict__ bpc,
    double* __restrict__ acc, int* __restrict__ num_pos,
    float* __restrict__ accLb, float* __restrict__ accCb,
    int* __restrict__ done) {
  __shared__ float4 s_pf[KA_CHUNK];
  __shared__ float s_t[NO * 5];
  __shared__ unsigned long long s_bp[256];
  const int b = blockIdx.y;
  const int tid = threadIdx.x;
  const int base = blockIdx.x * KA_CHUNK;

  if (blockIdx.x == 0 && b == 0) {
    if (tid < 4) acc[tid] = 0.0;
    else if (tid >= 32 && tid < 64) num_pos[tid - 32] = 0;
    else if (tid >= 64 && tid < 96) accLb[tid - 64] = 0.0f;
    else if (tid >= 96 && tid < 128) accCb[tid - 96] = 0.0f;
    else if (tid == 128) *done = 0;
  }

  for (int i = tid; i < NO * 5; i += 256) s_t[i] = targets[b * NO * 5 + i];

  #pragma unroll
  for (int k = 0; k < KA_CHUNK / 256; ++k) {
    const int p = base + k * 256 + tid;
    float4 pf;
    if (p < NP) {
      const float4 pr = ((const float4*)priors)[p];
      pf = make_float4(pr.x - pr.z * 0.5f, pr.y - pr.w * 0.5f,
                       pr.x + pr.z * 0.5f, pr.y + pr.w * 0.5f);
    } else {
      pf = make_float4(3.0f, 3.0f, 3.0f, 3.0f);  // degenerate: IoU == 0
    }
    s_pf[k * 256 + tid] = pf;
  }
  __syncthreads();

  const int wv = tid >> 6;
  const int lane = tid & 63;
  unsigned long long best = 0ull;
  if (lane < NO) {
    const float tx1 = s_t[lane * 5 + 0], ty1 = s_t[lane * 5 + 1];
    const float tx2 = s_t[lane * 5 + 2], ty2 = s_t[lane * 5 + 3];
    const float area_a = (tx2 - tx1) * (ty2 - ty1);
    const int i0 = wv * 256;
    #pragma unroll 8
    for (int i = 0; i < 256; ++i) {
      const float4 q = s_pf[i0 + i];
      const float wx = fmaxf(fminf(q.z, tx2) - fmaxf(q.x, tx1), 0.0f);
      const float wy = fmaxf(fminf(q.w, ty2) - fmaxf(q.y, ty1), 0.0f);
      const float inter = wx * wy;
      const float ab = (q.z - q.x) * (q.w - q.y);
      const float iou = __fdividef(inter, area_a + ab - inter);
      const unsigned p = (unsigned)(base + i0 + i);
      const unsigned long long pk =
          (((unsigned long long)__float_as_uint(iou)) << 32) |
          (unsigned long long)(0xFFFFFFFFu - p);
      if (pk > best) best = pk;
    }
  }
  s_bp[tid] = best;
  __syncthreads();
  if (tid < NO) {
    unsigned long long m = s_bp[tid];
    unsigned long long v = s_bp[64 + tid];  if (v > m) m = v;
    v = s_bp[128 + tid];                    if (v > m) m = v;
    v = s_bp[192 + tid];                    if (v > m) m = v;
    bpc[(size_t)blockIdx.x * (NB * NO) + b * NO + tid] = m;  // coalesced
  }
}

// ---------------- Kernel MS: match + DMA-staged lse + smooth-L1 ------------
// grid (48, NB), 512 thr = 8 waves; each wave owns 64 rows, staged as
// 8 tiles x 8 rows via global_load_lds into a per-wave LDS double buffer.
// Counted vmcnt(3): next tile's DMA stays in flight across consume.
__global__ __launch_bounds__(512) void kMS(
    const float* __restrict__ loc, const float* __restrict__ conf,
    const float* __restrict__ priors, const float* __restrict__ targets,
    const unsigned long long* __restrict__ bpc,
    float* __restrict__ mine, int* __restrict__ num_pos,
    float* __restrict__ accLb, float* __restrict__ accCb) {
  __shared__ float s_dma[8][2][768];     // per-wave double buffer (+pad)
  __shared__ float s_s[512];
  __shared__ int s_tpb[NO];
  __shared__ float sLw[8], sCw[8];
  __shared__ int sNw[8];

  const int tid = threadIdx.x;
  const int lane = tid & 63;
  const int w = tid >> 6;
  const int b = blockIdx.y;
  const int rowbase = blockIdx.x * 512 + w * 64;
  const int p = rowbase + lane;
  const bool valid = (p < NP);
  const int pc = valid ? p : NP - 1;
  const size_t grow = (size_t)b * NP + pc;
  const float* tb = targets + (size_t)b * (NO * 5);

  // phase 0: per-truth best prior (transposed bpc: coalesced reads)
  if (tid < NO) {
    unsigned long long m = 0ull;
    #pragma unroll
    for (int c = 0; c < NCH; ++c) {
      const unsigned long long v = bpc[(size_t)c * (NB * NO) + b * NO + tid];
      if (v > m) m = v;
    }
    s_tpb[tid] = (int)(0xFFFFFFFFu - (unsigned)(m & 0xFFFFFFFFull));
  }

  // lane l (<50) holds truth l in registers
  float ttx1 = 3.f, tty1 = 3.f, ttx2 = 3.f, tty2 = 3.f, tar = 0.f, tlab = 0.f;
  if (lane < NO) {
    ttx1 = tb[lane * 5 + 0]; tty1 = tb[lane * 5 + 1];
    ttx2 = tb[lane * 5 + 2]; tty2 = tb[lane * 5 + 3];
    tlab = tb[lane * 5 + 4];
    tar = (ttx2 - ttx1) * (tty2 - tty1);
  }
  const float4 pr = ((const float4*)priors)[pc];
  const float4 ldv = ((const float4*)loc)[grow];
  const float px1 = pr.x - pr.z * 0.5f, py1 = pr.y - pr.w * 0.5f;
  const float px2 = pr.x + pr.z * 0.5f, py2 = pr.y + pr.w * 0.5f;
  const float areab = (px2 - px1) * (py2 - py1);
  __syncthreads();
  const int tpb = (lane < NO) ? s_tpb[lane] : -1;

  // ---- DMA stage machinery (after barrier: no vmcnt(0) drain hits it) ----
  const unsigned* confu = (const unsigned*)conf;
  const size_t total_dw = (size_t)NB * NP * NC;
  const size_t max_dw = total_dw - 4;
  auto stage = [&](int bufsel, int t) {
    const size_t tile_dw = ((size_t)b * NP + (size_t)(rowbase + t * 8)) * NC;
    #pragma unroll
    for (int s = 0; s < 3; ++s) {
      size_t idx = tile_dw + (size_t)(s * 256 + lane * 4);
      if (idx > max_dw) idx = max_dw;    // 4-dw aligned clamp (tail)
      __builtin_amdgcn_global_load_lds(
          (const __attribute__((address_space(1))) unsigned*)(confu + idx),
          (__attribute__((address_space(3))) unsigned*)(&s_dma[w][bufsel][s * 256]),
          16, 0, 0);
    }
  };

  stage(0, 0);   // tile-0 DMA flies under the match loop (~2000 cy)

  // ---- match: memory-free 50-truth loop --------------------------------
  float bv = -1.0f;
  int bj = 0;
  #pragma unroll 2
  for (int j = 0; j < NO; ++j) {
    const float x1 = rl_f(ttx1, j), y1 = rl_f(tty1, j);
    const float x2 = rl_f(ttx2, j), y2 = rl_f(tty2, j);
    const float aa = rl_f(tar, j);
    const float wx = fmaxf(fminf(x2, px2) - fmaxf(x1, px1), 0.0f);
    const float wy = fmaxf(fminf(y2, py2) - fmaxf(y1, py1), 0.0f);
    const float inter = wx * wy;
    const float iou = __fdividef(inter, aa + areab - inter);
    if (iou > bv) { bv = iou; bj = j; }   // first-max tie-break
  }

  // ---- forced-match override via ballot scan (rare) --------------------
  int ovj = -1;
  unsigned long long M = __ballot((lane < NO) && ((unsigned)(tpb - rowbase) < 64u));
  while (M) {
    const int l = __ffsll((long long)M) - 1;
    M &= M - 1;
    const int r = __builtin_amdgcn_readlane(tpb, l) - rowbase;
    if (lane == r) ovj = l;              // ascending l -> last j wins
  }
  const int jm = (ovj >= 0) ? ovj : bj;
  const bool pos = valid && ((ovj >= 0) || (bv >= THR));
  const int j4 = jm << 2;
  const float lab = bp_f(tlab, j4);      // unconditional: all lanes active
  const float mx1 = bp_f(ttx1, j4), my1 = bp_f(tty1, j4);
  const float mx2 = bp_f(ttx2, j4), my2 = bp_f(tty2, j4);
  const int conft = pos ? ((int)lab + 1) : 0;

  // ---- smooth-L1 (positives only) --------------------------------------
  float sl1 = 0.0f;
  if (pos) {
    const float gcx = __fdividef((mx1 + mx2) * 0.5f - pr.x, 0.1f * pr.z);
    const float gcy = __fdividef((my1 + my2) * 0.5f - pr.y, 0.1f * pr.w);
    const float gw = __logf(__fdividef(mx2 - mx1, pr.z)) * 5.0f;
    const float gh = __logf(__fdividef(my2 - my1, pr.w)) * 5.0f;
    const float d0 = ldv.x - gcx, d1 = ldv.y - gcy;
    const float d2 = ldv.z - gw, d3 = ldv.w - gh;
    #pragma unroll
    for (int q = 0; q < 4; ++q) {
      const float d = (q == 0) ? d0 : (q == 1) ? d1 : (q == 2) ? d2 : d3;
      const float a = fabsf(d);
      sl1 += (a < 1.0f) ? 0.5f * d * d : a - 0.5f;
    }
  }

  // ---- lse consume: 8 tiles x 8 rows, double-buffered DMA ---------------
  const int r8 = lane >> 3;
  const int l8 = lane & 7;
  float gval = 0.0f;
  #pragma unroll 2
  for (int t = 0; t < 8; ++t) {
    if (t + 1 < 8) {
      stage((t + 1) & 1, t + 1);
      asm volatile("s_waitcnt vmcnt(3)" ::: "memory");  // tile t done; t+1 in flight
    } else {
      asm volatile("s_waitcnt vmcnt(0)" ::: "memory");
    }
    __builtin_amdgcn_sched_barrier(0);
    const float* buf = &s_dma[w][t & 1][0];
    const float* rowp = buf + r8 * 81;
    int kk = r8;                          // rotation: bank conflicts <=2-way
    float a0 = 0.0f, a1 = 0.0f;
    #pragma unroll
    for (int k = 0; k < 10; ++k) {
      const int c = l8 + 8 * kk;
      const float e = __expf(rowp[c]);
      if (k & 1) a1 += e; else a0 += e;
      kk = (kk == 9) ? 0 : kk + 1;
    }
    float s = a0 + a1;
    if (l8 == 0) s += __expf(rowp[80]);
    s += __shfl_xor(s, 1, 64);
    s += __shfl_xor(s, 2, 64);
    s += __shfl_xor(s, 4, 64);
    if (l8 == 0) s_s[w * 64 + t * 8 + r8] = s;
    if (r8 == t) gval = buf[l8 * 81 + conft];   // owner's gather, LDS-hot
  }
  const float myS = s_s[tid];            // wave-local; lgkmcnt ordered

  const float lca = __logf(myS) - gval;

  float sumL = 0.0f, sumC = 0.0f;
  int cnt = 0;
  if (valid) {
    mine[grow] = pos ? 0.0f : fmaxf(lca, 0.0f);
    if (pos) { cnt = 1; sumC = lca; sumL = sl1; }
  }

  // ---- wave + block reduce, one atomic set per block --------------------
  #pragma unroll
  for (int m = 1; m <= 32; m <<= 1) {
    sumL += __shfl_xor(sumL, m, 64);
    sumC += __shfl_xor(sumC, m, 64);
    cnt  += __shfl_xor(cnt, m, 64);
  }
  if (lane == 0) { sLw[w] = sumL; sCw[w] = sumC; sNw[w] = cnt; }
  __syncthreads();
  if (tid == 0) {
    float L = 0.0f, C = 0.0f;
    int n = 0;
    #pragma unroll
    for (int q = 0; q < 8; ++q) { L += sLw[q]; C += sCw[q]; n += sNw[q]; }
    if (L != 0.0f) atomicAdd(&accLb[b], L);
    if (C != 0.0f) atomicAdd(&accCb[b], C);
    if (n) atomicAdd(&num_pos[b], n);
  }
}

// ---------------- Kernel D: top-K radix select + fused finalize ------------
__global__ __launch_bounds__(512) void kD(
    const float* __restrict__ mine, const int* __restrict__ num_pos,
    double* __restrict__ acc, int* __restrict__ done,
    const float* __restrict__ accLb, const float* __restrict__ accCb,
    float* __restrict__ out) {
  const int b = blockIdx.x;
  const int tid = threadIdx.x;
  const uint4* vb4 = (const uint4*)(mine + (size_t)b * NP);

  unsigned vals[48];
  #pragma unroll
  for (int k = 0; k < 12; ++k) {
    const int i = tid + k * 512;
    uint4 q = make_uint4(0u, 0u, 0u, 0u);
    if (i < NP / 4) q = vb4[i];          // NP/4 == 6141 exactly
    vals[4 * k + 0] = q.x; vals[4 * k + 1] = q.y;
    vals[4 * k + 2] = q.z; vals[4 * k + 3] = q.w;
  }

  const int K = min(3 * num_pos[b], NP - 1);

  __shared__ int s_w[2][8];
  unsigned prefix = 0u;
  int remaining = K;

  for (int bit = 30; bit >= 0; --bit) {
    const unsigned want = (prefix >> bit) | 1u;
    int cnt = 0;
    #pragma unroll
    for (int k = 0; k < 48; ++k) cnt += ((vals[k] >> bit) == want) ? 1 : 0;
    #pragma unroll
    for (int m = 32; m >= 1; m >>= 1) cnt += __shfl_xor(cnt, m, 64);
    const int buf = bit & 1;
    if ((tid & 63) == 0) s_w[buf][tid >> 6] = cnt;
    __syncthreads();
    int total = 0;
    #pragma unroll
    for (int w = 0; w < 8; ++w) total += s_w[buf][w];
    if (total >= remaining) prefix |= (1u << bit);
    else remaining -= total;
  }

  if (K > 0) {
    const float t = __uint_as_float(prefix);
    double sg = 0.0;
    int cg = 0;
    #pragma unroll
    for (int k = 0; k < 48; ++k) {
      const float f = __uint_as_float(vals[k]);
      if (f > t) { sg += (double)f; cg++; }
    }
    #pragma unroll
    for (int m = 32; m >= 1; m >>= 1) {
      sg += __shfl_xor(sg, m, 64);
      cg += __shfl_xor(cg, m, 64);
    }
    __shared__ double s_sd[8];
    __shared__ int s_sc[8];
    const int wid = tid >> 6;
    if ((tid & 63) == 0) { s_sd[wid] = sg; s_sc[wid] = cg; }
    __syncthreads();
    if (tid == 0) {
      double S = 0.0;
      int C = 0;
      for (int w = 0; w < 8; ++w) { S += s_sd[w]; C += s_sc[w]; }
      S += (double)(K - C) * (double)t;
      atomicAdd(&acc[2], S);
    }
  }

  // ---- last block finalizes ---------------------------------------------
  __shared__ int s_last;
  __syncthreads();
  if (tid == 0) {
    __threadfence();
    s_last = (atomicAdd(done, 1) == NB - 1) ? 1 : 0;
  }
  __syncthreads();
  if (s_last && tid < 64) {
    __threadfence();
    int n = 0;
    float L = 0.0f, C = 0.0f;
    if (tid < NB) { n = num_pos[tid]; L = accLb[tid]; C = accCb[tid]; }
    #pragma unroll
    for (int m = 32; m >= 1; m >>= 1) {
      n += __shfl_xor(n, m, 64);
      L += __shfl_xor(L, m, 64);
      C += __shfl_xor(C, m, 64);
    }
    if (tid == 0) {
      const double S = atomicAdd(&acc[2], 0.0);  // coherent read
      const double Nf = (double)n;
      out[0] = (float)((double)L / Nf);
      out[1] = (float)(((double)C + S) / Nf);
    }
  }
}

extern "C" void kernel_launch(void* const* d_in, const int* in_sizes, int n_in,
                              void* d_out, int out_size, void* d_ws, size_t ws_size,
                              hipStream_t stream) {
  const float* loc     = (const float*)d_in[0];
  const float* conf    = (const float*)d_in[1];
  const float* priors  = (const float*)d_in[2];
  const float* targets = (const float*)d_in[3];
  float* out = (float*)d_out;

  char* ws = (char*)d_ws;
  double* acc   = (double*)ws;
  int* num_pos  = (int*)(ws + 32);
  float* accLb  = (float*)(ws + 160);
  float* accCb  = (float*)(ws + 288);
  int* done     = (int*)(ws + 416);
  unsigned long long* bpc = (unsigned long long*)(ws + 552);
  const size_t hdr = 307760;             // 552 + 307200, padded to 16B
  float* mine  = (float*)(ws + hdr);

  dim3 gA(NCH, NB);
  kA<<<gA, 256, 0, stream>>>(priors, targets, bpc,
                             acc, num_pos, accLb, accCb, done);

  dim3 gM((NP + 511) / 512, NB);
  kMS<<<gM, 512, 0, stream>>>(loc, conf, priors, targets, bpc,
                              mine, num_pos, accLb, accCb);

  kD<<<NB, 512, 0, stream>>>(mine, num_pos, acc, done, accLb, accCb, out);
}